// Round 4
// baseline (9996.374 us; speedup 1.0000x reference)
//
#include <hip/hip_runtime.h>

#define S_TOT 2304
#define D_TOT 3072
#define NH    24
#define HD    128
#define BLK_R 2048
#define TIP   128
#define DIP   4096

typedef __attribute__((ext_vector_type(4))) float f4;
typedef __attribute__((ext_vector_type(8))) short bh8;
typedef unsigned short u16;
typedef unsigned int   u32;
typedef unsigned long long u64;

__device__ __forceinline__ u16 f2bf(float f) {
    u32 u = __float_as_uint(f);
    u32 r = (u + 0x7fffu + ((u >> 16) & 1u)) >> 16;
    return (u16)r;
}
__device__ __forceinline__ uint4 pack8u(float4 a, float4 b) {
    uint4 u;
    u.x = (u32)f2bf(a.x) | ((u32)f2bf(a.y) << 16);
    u.y = (u32)f2bf(a.z) | ((u32)f2bf(a.w) << 16);
    u.z = (u32)f2bf(b.x) | ((u32)f2bf(b.y) << 16);
    u.w = (u32)f2bf(b.z) | ((u32)f2bf(b.w) << 16);
    return u;
}
__device__ __forceinline__ bh8 pack8v(float4 a, float4 b) {
    bh8 v;
    v[0] = (short)f2bf(a.x); v[1] = (short)f2bf(a.y);
    v[2] = (short)f2bf(a.z); v[3] = (short)f2bf(a.w);
    v[4] = (short)f2bf(b.x); v[5] = (short)f2bf(b.y);
    v[6] = (short)f2bf(b.z); v[7] = (short)f2bf(b.w);
    return v;
}

// ---------------- GEMM: C[M][N] (+)= A[M][K] @ B[N][K]^T + bias ----------------
// A, B, bias f32 (converted to bf16 during LDS staging); C f32.
// 128x128 tile, BK=64, 4 waves (2x2), 4x4 mfma 16x16x32 each.
// mode 0: store (+bias). mode 1: C += (single writer). mode 2: atomicAdd (split-K, C pre-zeroed).
__global__ __launch_bounds__(256)
void gemm_f32(const float* __restrict__ A, const float* __restrict__ B,
              const float* __restrict__ bias, float* __restrict__ C,
              int M, int N, int K, int mode, int ksplit)
{
    __shared__ u16 As[128 * 64];
    __shared__ u16 Bs[128 * 64];
    const int tid  = threadIdx.x;
    const int wv   = tid >> 6;
    const int lane = tid & 63;
    const int quad = lane >> 4;
    const int l16  = lane & 15;
    const int wm   = (wv >> 1) << 6;
    const int wn   = (wv & 1) << 6;
    const int m0   = blockIdx.x << 7;
    const int n0   = blockIdx.y << 7;
    const int kch  = K / ksplit;
    const int kbeg = blockIdx.z * kch;
    const int kend = kbeg + kch;

    f4 acc[4][4] = {};

    for (int k0 = kbeg; k0 < kend; k0 += 64) {
#pragma unroll
        for (int p = 0; p < 4; ++p) {
            int idx = (p << 11) + (tid << 3);
            int r = idx >> 6, c = idx & 63;
            const float* ap = A + (size_t)(m0 + r) * K + k0 + c;
            *(uint4*)(&As[idx]) = pack8u(*(const float4*)ap, *(const float4*)(ap + 4));
            const float* bp = B + (size_t)(n0 + r) * K + k0 + c;
            *(uint4*)(&Bs[idx]) = pack8u(*(const float4*)bp, *(const float4*)(bp + 4));
        }
        __syncthreads();
#pragma unroll
        for (int kk = 0; kk < 2; ++kk) {
            bh8 a[4], b[4];
#pragma unroll
            for (int i = 0; i < 4; ++i)
                a[i] = *(const bh8*)(&As[(wm + (i << 4) + l16) * 64 + (kk << 5) + (quad << 3)]);
#pragma unroll
            for (int i = 0; i < 4; ++i)
                b[i] = *(const bh8*)(&Bs[(wn + (i << 4) + l16) * 64 + (kk << 5) + (quad << 3)]);
#pragma unroll
            for (int mt = 0; mt < 4; ++mt)
#pragma unroll
                for (int nt = 0; nt < 4; ++nt)
                    acc[mt][nt] = __builtin_amdgcn_mfma_f32_16x16x32_bf16(a[mt], b[nt], acc[mt][nt], 0, 0, 0);
        }
        __syncthreads();
    }
#pragma unroll
    for (int mt = 0; mt < 4; ++mt) {
#pragma unroll
        for (int nt = 0; nt < 4; ++nt) {
            int n = n0 + wn + (nt << 4) + l16;
            float bs = bias ? bias[n] : 0.0f;
#pragma unroll
            for (int r = 0; r < 4; ++r) {
                int m = m0 + wm + (mt << 4) + (quad << 2) + r;
                size_t o = (size_t)m * N + n;
                float v = acc[mt][nt][r] + bs;
                if (mode == 0)      C[o] = v;
                else if (mode == 1) C[o] += v;
                else                atomicAdd(&C[o], v);
            }
        }
    }
}

// ---------------- LoRA down: T1[s][r] = sum_d X[2048+s][d]*Dwn[r][d], f32 out ----------------
// 32 blocks x 4 waves = 128 waves; each wave one 16x16 tile (mt 0..15, nt 0..7), K=3072.
__global__ __launch_bounds__(256)
void lora_down_k(const float* __restrict__ X, const float* __restrict__ Dwn, float* __restrict__ T1)
{
    int wv = threadIdx.x >> 6, lane = threadIdx.x & 63;
    int quad = lane >> 4, l16 = lane & 15;
    int gw = blockIdx.x * 4 + wv;          // 0..127
    int mt = gw >> 3, nt = gw & 7;
    const float* ap = X + (size_t)(BLK_R + (mt << 4) + l16) * D_TOT + (quad << 3);
    const float* bp = Dwn + (size_t)((nt << 4) + l16) * D_TOT + (quad << 3);
    f4 acc = {};
    for (int c = 0; c < 96; ++c) {
        bh8 a = pack8v(*(const float4*)(ap + (c << 5)), *(const float4*)(ap + (c << 5) + 4));
        bh8 b = pack8v(*(const float4*)(bp + (c << 5)), *(const float4*)(bp + (c << 5) + 4));
        acc = __builtin_amdgcn_mfma_f32_16x16x32_bf16(a, b, acc, 0, 0, 0);
    }
#pragma unroll
    for (int r = 0; r < 4; ++r) {
        int s  = (mt << 4) + (quad << 2) + r;
        int rr = (nt << 4) + l16;
        T1[(size_t)s * 128 + rr] = acc[r];
    }
}

// ---------------- RMSNorm (+f32 weight) + optional RoPE, IN-PLACE on f32 [Slen][3072] ----------------
// one wave per (s, h) pair; lane holds dims 2*lane, 2*lane+1 of the 128-dim head row.
template <int ROPE>
__global__ __launch_bounds__(256)
void norm_rope_f32(float* __restrict__ X, const float* __restrict__ w,
                   const float* __restrict__ ct, const float* __restrict__ st)
{
    int g = blockIdx.x * 4 + (threadIdx.x >> 6);
    int lane = threadIdx.x & 63;
    int s = g / NH, h = g % NH;
    float* xp = X + (size_t)s * D_TOT + (h << 7) + (lane << 1);
    float2 xv = *(float2*)xp;
    float ss = xv.x * xv.x + xv.y * xv.y;
#pragma unroll
    for (int off = 1; off <= 32; off <<= 1) ss += __shfl_xor(ss, off);
    float invr = rsqrtf(ss * (1.0f / 128.0f) + 1e-5f);
    float a = xv.x * invr, b = xv.y * invr;
    if (w) { a *= w[lane << 1]; b *= w[(lane << 1) + 1]; }
    if (ROPE) {
        float c0 = ct[(size_t)s * HD + (lane << 1)], c1 = ct[(size_t)s * HD + (lane << 1) + 1];
        float n0 = st[(size_t)s * HD + (lane << 1)], n1 = st[(size_t)s * HD + (lane << 1) + 1];
        float o0 = a * c0 - b * n0;
        float o1 = b * c1 + a * n1;
        a = o0; b = o1;
    }
    float2 ov; ov.x = a; ov.y = b;
    *(float2*)xp = ov;
}

// ---------------- naive streaming-softmax attention (f32 VALU, correctness-first) ----------------
// Q/K/V are f32 [Lrows][3072], head h = cols [h*128, h*128+128). 16 q-rows per block
// (4 per wave, lane owns dims 2*lane, 2*lane+1). K/V streamed in 32-key LDS tiles.
// Main attn: q rows >= 2048 only see keys [cond_k0, Lk). Out f32 [S_TOT][3072]; accum=1 RMWs.
__global__ __launch_bounds__(256)
void attn_naive(const float* __restrict__ Q, const float* __restrict__ Kv,
                const float* __restrict__ Vv, float* __restrict__ Out,
                int Lk, int cond_k0, int accum)
{
    __shared__ float Ks[32][128];
    __shared__ float Vs[32][128];
    const int h = blockIdx.y;
    const int qb = blockIdx.x << 4;
    const int tid = threadIdx.x;
    const int wv = tid >> 6, lane = tid & 63;
    const float sc2 = 0.08838834764831845f * 1.4426950408889634f;  // 1/sqrt(128) * log2(e)

    float q0[4][2], o[4][2], m[4], l[4];
#pragma unroll
    for (int r = 0; r < 4; ++r) {
        int row = qb + (wv << 2) + r;
        float2 t = *(const float2*)(Q + (size_t)row * D_TOT + (h << 7) + (lane << 1));
        q0[r][0] = t.x * sc2; q0[r][1] = t.y * sc2;
        m[r] = -1e30f; l[r] = 0.0f; o[r][0] = 0.0f; o[r][1] = 0.0f;
    }

    const int k0 = (qb >= BLK_R) ? cond_k0 : 0;
    for (int key0 = k0; key0 < Lk; key0 += 32) {
#pragma unroll
        for (int i = 0; i < 4; ++i) {
            int idx = (i << 10) + (tid << 2);
            int rr = idx >> 7, cc = idx & 127;
            *(float4*)&Ks[rr][cc] = *(const float4*)(Kv + (size_t)(key0 + rr) * D_TOT + (h << 7) + cc);
            *(float4*)&Vs[rr][cc] = *(const float4*)(Vv + (size_t)(key0 + rr) * D_TOT + (h << 7) + cc);
        }
        __syncthreads();
        for (int kk = 0; kk < 32; ++kk) {
            float2 kv = *(const float2*)&Ks[kk][lane << 1];
            float2 vv = *(const float2*)&Vs[kk][lane << 1];
            float s[4];
#pragma unroll
            for (int r = 0; r < 4; ++r) s[r] = q0[r][0] * kv.x + q0[r][1] * kv.y;
#pragma unroll
            for (int off = 1; off <= 32; off <<= 1)
#pragma unroll
                for (int r = 0; r < 4; ++r) s[r] += __shfl_xor(s[r], off);
#pragma unroll
            for (int r = 0; r < 4; ++r) {
                float mn = fmaxf(m[r], s[r]);
                float al = exp2f(m[r] - mn);
                float p  = exp2f(s[r] - mn);
                m[r] = mn;
                l[r] = l[r] * al + p;
                o[r][0] = o[r][0] * al + p * vv.x;
                o[r][1] = o[r][1] * al + p * vv.y;
            }
        }
        __syncthreads();
    }
#pragma unroll
    for (int r = 0; r < 4; ++r) {
        int row = qb + (wv << 2) + r;
        float il = 1.0f / l[r];
        float a = o[r][0] * il, b = o[r][1] * il;
        size_t oo = (size_t)row * D_TOT + (h << 7) + (lane << 1);
        if (accum) { a += Out[oo]; b += Out[oo + 1]; }
        float2 ov; ov.x = a; ov.y = b;
        *(float2*)(&Out[oo]) = ov;
    }
}

// ---------------- workspace layout (byte offsets), total ~88.5 MB ----------------
static const u64 B_QF   = 0;           // fp32 [2304][3072]
static const u64 B_KF   = 28311552;
static const u64 B_VF   = 56623104;
static const u64 B_KIPF = 84934656;    // fp32 [128][3072]
static const u64 B_VIPF = 86507520;
static const u64 B_T1   = 88080384;    // fp32 [3][256][128]

extern "C" void kernel_launch(void* const* d_in, const int* in_sizes, int n_in,
                              void* d_out, int out_size, void* d_ws, size_t ws_size,
                              hipStream_t stream) {
    (void)in_sizes; (void)n_in; (void)out_size; (void)ws_size;
    const float* x    = (const float*)d_in[0];
    const float* img  = (const float*)d_in[1];
    const float* rc   = (const float*)d_in[2];
    const float* rsn  = (const float*)d_in[3];
    const float* Wq   = (const float*)d_in[4];
    const float* bq   = (const float*)d_in[5];
    const float* Wk   = (const float*)d_in[6];
    const float* bk   = (const float*)d_in[7];
    const float* Wv   = (const float*)d_in[8];
    const float* bv   = (const float*)d_in[9];
    const float* qdn  = (const float*)d_in[10];
    const float* qup  = (const float*)d_in[11];
    const float* kdn  = (const float*)d_in[12];
    const float* kup  = (const float*)d_in[13];
    const float* vdn  = (const float*)d_in[14];
    const float* vup  = (const float*)d_in[15];
    const float* nqw  = (const float*)d_in[16];
    const float* nkw  = (const float*)d_in[17];
    const float* Wkip = (const float*)d_in[18];
    const float* Wvip = (const float*)d_in[19];

    float* qf   = (float*)((char*)d_ws + B_QF);
    float* kf   = (float*)((char*)d_ws + B_KF);
    float* vf   = (float*)((char*)d_ws + B_VF);
    float* kipf = (float*)((char*)d_ws + B_KIPF);
    float* vipf = (float*)((char*)d_ws + B_VIPF);
    float* t1   = (float*)((char*)d_ws + B_T1);
    float* outf = (float*)d_out;

    // zero the split-K atomic accumulation targets
    hipMemsetAsync((char*)d_ws + B_KIPF, 0, 2 * 1572864, stream);

    // 1) QKV projections: [2304][3072] = x @ W^T + bias (fp32 out)
    gemm_f32<<<dim3(18, 24, 1), dim3(256), 0, stream>>>(x, Wq, bq, qf, S_TOT, D_TOT, D_TOT, 0, 1);
    gemm_f32<<<dim3(18, 24, 1), dim3(256), 0, stream>>>(x, Wk, bk, kf, S_TOT, D_TOT, D_TOT, 0, 1);
    gemm_f32<<<dim3(18, 24, 1), dim3(256), 0, stream>>>(x, Wv, bv, vf, S_TOT, D_TOT, D_TOT, 0, 1);

    // 2) LoRA: down (t1 = x_cond @ down^T), then up (+= into rows 2048..2303)
    lora_down_k<<<dim3(32), dim3(256), 0, stream>>>(x, qdn, t1);
    lora_down_k<<<dim3(32), dim3(256), 0, stream>>>(x, kdn, t1 + 32768);
    lora_down_k<<<dim3(32), dim3(256), 0, stream>>>(x, vdn, t1 + 65536);
    gemm_f32<<<dim3(2, 24, 1), dim3(256), 0, stream>>>(t1,         qup, nullptr, qf + (size_t)BLK_R * D_TOT, 256, D_TOT, 128, 1, 1);
    gemm_f32<<<dim3(2, 24, 1), dim3(256), 0, stream>>>(t1 + 32768, kup, nullptr, kf + (size_t)BLK_R * D_TOT, 256, D_TOT, 128, 1, 1);
    gemm_f32<<<dim3(2, 24, 1), dim3(256), 0, stream>>>(t1 + 65536, vup, nullptr, vf + (size_t)BLK_R * D_TOT, 256, D_TOT, 128, 1, 1);

    // 3) IP projections: [128][3072] = img @ W_ip^T (split-K=8, atomic into zeroed fp32)
    gemm_f32<<<dim3(1, 24, 8), dim3(256), 0, stream>>>(img, Wkip, nullptr, kipf, TIP, D_TOT, DIP, 2, 8);
    gemm_f32<<<dim3(1, 24, 8), dim3(256), 0, stream>>>(img, Wvip, nullptr, vipf, TIP, D_TOT, DIP, 2, 8);

    // 4) norm (+rope) in place, per (s,h) head-row
    norm_rope_f32<1><<<dim3(13824), dim3(256), 0, stream>>>(qf, nqw, rc, rsn);     // 2304*24/4
    norm_rope_f32<1><<<dim3(13824), dim3(256), 0, stream>>>(kf, nkw, rc, rsn);
    norm_rope_f32<0><<<dim3(768),   dim3(256), 0, stream>>>(kipf, nullptr, nullptr, nullptr);  // 128*24/4

    // 5) attention: main writes f32 out; IP attention accumulates (RMW)
    attn_naive<<<dim3(144, 24), dim3(256), 0, stream>>>(qf, kf,   vf,   outf, S_TOT, BLK_R, 0);
    attn_naive<<<dim3(144, 24), dim3(256), 0, stream>>>(qf, kipf, vipf, outf, TIP,   0,     1);
}

// Round 5
// 1759.552 us; speedup vs baseline: 5.6812x; 5.6812x over previous
//
#include <hip/hip_runtime.h>

#define S_TOT 2304
#define D_TOT 3072
#define NH    24
#define HD    128
#define BLK_R 2048
#define TIP   128
#define DIP   4096

typedef __attribute__((ext_vector_type(4))) float f4;
typedef __attribute__((ext_vector_type(8))) short bh8;
typedef unsigned short u16;
typedef unsigned int   u32;
typedef unsigned long long u64;

__device__ __forceinline__ u16 f2bf(float f) {
    u32 u = __float_as_uint(f);
    u32 r = (u + 0x7fffu + ((u >> 16) & 1u)) >> 16;
    return (u16)r;
}
__device__ __forceinline__ uint4 pack8u(float4 a, float4 b) {
    uint4 u;
    u.x = (u32)f2bf(a.x) | ((u32)f2bf(a.y) << 16);
    u.y = (u32)f2bf(a.z) | ((u32)f2bf(a.w) << 16);
    u.z = (u32)f2bf(b.x) | ((u32)f2bf(b.y) << 16);
    u.w = (u32)f2bf(b.z) | ((u32)f2bf(b.w) << 16);
    return u;
}
__device__ __forceinline__ bh8 pack8v(float4 a, float4 b) {
    bh8 v;
    v[0] = (short)f2bf(a.x); v[1] = (short)f2bf(a.y);
    v[2] = (short)f2bf(a.z); v[3] = (short)f2bf(a.w);
    v[4] = (short)f2bf(b.x); v[5] = (short)f2bf(b.y);
    v[6] = (short)f2bf(b.z); v[7] = (short)f2bf(b.w);
    return v;
}

// ---------------- GEMM: C[M][N] (+)= A[M][K] @ B[N][K]^T + bias ----------------
// A, B, bias f32 (converted to bf16 during LDS staging); C f32.
// 128x128 tile, BK=64, 4 waves (2x2), 4x4 mfma 16x16x32 each.
// mode 0: store (+bias). mode 1: C += (single writer). mode 2: atomicAdd (split-K, C pre-zeroed).
__global__ __launch_bounds__(256)
void gemm_f32(const float* __restrict__ A, const float* __restrict__ B,
              const float* __restrict__ bias, float* __restrict__ C,
              int M, int N, int K, int mode, int ksplit)
{
    __shared__ u16 As[128 * 64];
    __shared__ u16 Bs[128 * 64];
    const int tid  = threadIdx.x;
    const int wv   = tid >> 6;
    const int lane = tid & 63;
    const int quad = lane >> 4;
    const int l16  = lane & 15;
    const int wm   = (wv >> 1) << 6;
    const int wn   = (wv & 1) << 6;
    const int m0   = blockIdx.x << 7;
    const int n0   = blockIdx.y << 7;
    const int kch  = K / ksplit;
    const int kbeg = blockIdx.z * kch;
    const int kend = kbeg + kch;

    f4 acc[4][4] = {};

    for (int k0 = kbeg; k0 < kend; k0 += 64) {
#pragma unroll
        for (int p = 0; p < 4; ++p) {
            int idx = (p << 11) + (tid << 3);
            int r = idx >> 6, c = idx & 63;
            const float* ap = A + (size_t)(m0 + r) * K + k0 + c;
            *(uint4*)(&As[idx]) = pack8u(*(const float4*)ap, *(const float4*)(ap + 4));
            const float* bp = B + (size_t)(n0 + r) * K + k0 + c;
            *(uint4*)(&Bs[idx]) = pack8u(*(const float4*)bp, *(const float4*)(bp + 4));
        }
        __syncthreads();
#pragma unroll
        for (int kk = 0; kk < 2; ++kk) {
            bh8 a[4], b[4];
#pragma unroll
            for (int i = 0; i < 4; ++i)
                a[i] = *(const bh8*)(&As[(wm + (i << 4) + l16) * 64 + (kk << 5) + (quad << 3)]);
#pragma unroll
            for (int i = 0; i < 4; ++i)
                b[i] = *(const bh8*)(&Bs[(wn + (i << 4) + l16) * 64 + (kk << 5) + (quad << 3)]);
#pragma unroll
            for (int mt = 0; mt < 4; ++mt)
#pragma unroll
                for (int nt = 0; nt < 4; ++nt)
                    acc[mt][nt] = __builtin_amdgcn_mfma_f32_16x16x32_bf16(a[mt], b[nt], acc[mt][nt], 0, 0, 0);
        }
        __syncthreads();
    }
#pragma unroll
    for (int mt = 0; mt < 4; ++mt) {
#pragma unroll
        for (int nt = 0; nt < 4; ++nt) {
            int n = n0 + wn + (nt << 4) + l16;
            float bs = bias ? bias[n] : 0.0f;
#pragma unroll
            for (int r = 0; r < 4; ++r) {
                int m = m0 + wm + (mt << 4) + (quad << 2) + r;
                size_t o = (size_t)m * N + n;
                float v = acc[mt][nt][r] + bs;
                if (mode == 0)      C[o] = v;
                else if (mode == 1) C[o] += v;
                else                atomicAdd(&C[o], v);
            }
        }
    }
}

// ---------------- LoRA down: T1[s][r] = sum_d X[2048+s][d]*Dwn[r][d], f32 out ----------------
__global__ __launch_bounds__(256)
void lora_down_k(const float* __restrict__ X, const float* __restrict__ Dwn, float* __restrict__ T1)
{
    int wv = threadIdx.x >> 6, lane = threadIdx.x & 63;
    int quad = lane >> 4, l16 = lane & 15;
    int gw = blockIdx.x * 4 + wv;          // 0..127
    int mt = gw >> 3, nt = gw & 7;
    const float* ap = X + (size_t)(BLK_R + (mt << 4) + l16) * D_TOT + (quad << 3);
    const float* bp = Dwn + (size_t)((nt << 4) + l16) * D_TOT + (quad << 3);
    f4 acc = {};
    for (int c = 0; c < 96; ++c) {
        bh8 a = pack8v(*(const float4*)(ap + (c << 5)), *(const float4*)(ap + (c << 5) + 4));
        bh8 b = pack8v(*(const float4*)(bp + (c << 5)), *(const float4*)(bp + (c << 5) + 4));
        acc = __builtin_amdgcn_mfma_f32_16x16x32_bf16(a, b, acc, 0, 0, 0);
    }
#pragma unroll
    for (int r = 0; r < 4; ++r) {
        int s  = (mt << 4) + (quad << 2) + r;
        int rr = (nt << 4) + l16;
        T1[(size_t)s * 128 + rr] = acc[r];
    }
}

// ---------------- RMSNorm (+f32 weight) + optional RoPE; f32 [Slen][3072] -> bf16 [H][Slen][128]
template <int ROPE>
__global__ __launch_bounds__(256)
void norm_rope_k(const float* __restrict__ X, const float* __restrict__ w,
                 const float* __restrict__ ct, const float* __restrict__ st,
                 u16* __restrict__ Out, int Slen)
{
    int g = blockIdx.x * 4 + (threadIdx.x >> 6);
    int lane = threadIdx.x & 63;
    int s = g / NH, h = g % NH;
    const float* xp = X + (size_t)s * D_TOT + (h << 7) + (lane << 1);
    float2 xv = *(const float2*)xp;
    float ss = xv.x * xv.x + xv.y * xv.y;
#pragma unroll
    for (int off = 1; off <= 32; off <<= 1) ss += __shfl_xor(ss, off);
    float invr = rsqrtf(ss * (1.0f / 128.0f) + 1e-5f);
    float a = xv.x * invr, b = xv.y * invr;
    if (w) { a *= w[lane << 1]; b *= w[(lane << 1) + 1]; }
    float o0 = a, o1 = b;
    if (ROPE) {
        float c0 = ct[(size_t)s * HD + (lane << 1)], c1 = ct[(size_t)s * HD + (lane << 1) + 1];
        float n0 = st[(size_t)s * HD + (lane << 1)], n1 = st[(size_t)s * HD + (lane << 1) + 1];
        o0 = a * c0 - b * n0;
        o1 = b * c1 + a * n1;
    }
    size_t oo = ((size_t)h * Slen + s) * HD + (lane << 1);
    u32 pack = (u32)f2bf(o0) | ((u32)f2bf(o1) << 16);
    *(u32*)(&Out[oo]) = pack;
}

// ---------------- V transpose: f32 [Slen][3072] -> bf16 Vt[H][HD][Slen] ----------------
__global__ __launch_bounds__(256)
void transpose_v_k(const float* __restrict__ V, u16* __restrict__ Vt, int Slen)
{
    __shared__ u16 tile[64][130];
    int h = blockIdx.y;
    int s0 = blockIdx.x << 6;
    int tid = threadIdx.x;
#pragma unroll
    for (int p = 0; p < 32; ++p) {
        int flat = (p << 8) + tid;
        int si = flat >> 7, d = flat & 127;
        tile[si][d] = f2bf(V[(size_t)(s0 + si) * D_TOT + (h << 7) + d]);
    }
    __syncthreads();
#pragma unroll
    for (int p = 0; p < 32; ++p) {
        int flat = (p << 8) + tid;
        int d = flat >> 6, si = flat & 63;
        Vt[((size_t)(h << 7) + d) * Slen + s0 + si] = tile[si][d];
    }
}

// ---------------- MFMA flash attention (per-wave 16 q-rows, 32-key tiles) ----------------
// Qb [H][S_TOT][128], Kb [H][Lk][128], Vt [H][128][Lk]; Out f32 [S_TOT][3072].
// Q rows >= 2048 start at key tile cond_start (64 for main attn, 0 for IP). accum=1 RMWs Out.
__global__ __launch_bounds__(256)
void attn_k(const u16* __restrict__ Qb, const u16* __restrict__ Kb,
            const u16* __restrict__ Vt, float* __restrict__ Out,
            int Lk, int cond_start, int accum)
{
    __shared__ u16 Pl[4][16 * 40];   // per-wave P tile, rows padded to 40
    const int h = blockIdx.y;
    const int qt = blockIdx.x;
    const int wv = threadIdx.x >> 6;
    const int lane = threadIdx.x & 63;
    const int quad = lane >> 4, l16 = lane & 15;
    const int sb = (qt << 6) + (wv << 4);
    const float sc2 = 0.08838834764831845f * 1.4426950408889634f;  // 1/sqrt(128) * log2(e)

    bh8 qf[4];
    const u16* qp = Qb + ((size_t)h * S_TOT + sb + l16) * HD + (quad << 3);
#pragma unroll
    for (int c = 0; c < 4; ++c) qf[c] = *(const bh8*)(qp + (c << 5));

    f4 o[8] = {};
    float mrow[4] = {-1e30f, -1e30f, -1e30f, -1e30f};
    float lrow[4] = {0.f, 0.f, 0.f, 0.f};
    u16* pl = &Pl[wv][0];

    const int kt0 = (sb >= BLK_R) ? cond_start : 0;
    const int ktN = Lk >> 5;
    for (int kt = kt0; kt < ktN; ++kt) {
        int key0 = kt << 5;
        f4 s0 = {}, s1 = {};
        const u16* kp = Kb + ((size_t)h * Lk + key0 + l16) * HD + (quad << 3);
#pragma unroll
        for (int c = 0; c < 4; ++c) {
            bh8 b0 = *(const bh8*)(kp + (c << 5));
            bh8 b1 = *(const bh8*)(kp + 2048 + (c << 5));   // +16 key rows * 128
            s0 = __builtin_amdgcn_mfma_f32_16x16x32_bf16(qf[c], b0, s0, 0, 0, 0);
            s1 = __builtin_amdgcn_mfma_f32_16x16x32_bf16(qf[c], b1, s1, 0, 0, 0);
        }
        float p0[4], p1[4], mx[4], rsum[4], alpha[4];
#pragma unroll
        for (int r = 0; r < 4; ++r) {
            s0[r] *= sc2; s1[r] *= sc2;
            mx[r] = fmaxf(s0[r], s1[r]);
        }
#pragma unroll
        for (int off = 1; off <= 8; off <<= 1)
#pragma unroll
            for (int r = 0; r < 4; ++r) mx[r] = fmaxf(mx[r], __shfl_xor(mx[r], off));
#pragma unroll
        for (int r = 0; r < 4; ++r) {
            float mn = fmaxf(mrow[r], mx[r]);
            alpha[r] = exp2f(mrow[r] - mn);
            mrow[r] = mn;
            p0[r] = exp2f(s0[r] - mn);
            p1[r] = exp2f(s1[r] - mn);
            rsum[r] = p0[r] + p1[r];
        }
#pragma unroll
        for (int off = 1; off <= 8; off <<= 1)
#pragma unroll
            for (int r = 0; r < 4; ++r) rsum[r] += __shfl_xor(rsum[r], off);
#pragma unroll
        for (int r = 0; r < 4; ++r) lrow[r] = lrow[r] * alpha[r] + rsum[r];
#pragma unroll
        for (int dt = 0; dt < 8; ++dt)
#pragma unroll
            for (int r = 0; r < 4; ++r) o[dt][r] *= alpha[r];
        // P (C-layout) -> LDS -> A-layout
#pragma unroll
        for (int r = 0; r < 4; ++r) {
            pl[((quad << 2) + r) * 40 + l16]      = f2bf(p0[r]);
            pl[((quad << 2) + r) * 40 + 16 + l16] = f2bf(p1[r]);
        }
        bh8 pa = *(const bh8*)(pl + l16 * 40 + (quad << 3));
        const u16* vp = Vt + ((size_t)(h << 7) + l16) * Lk + key0 + (quad << 3);
#pragma unroll
        for (int dt = 0; dt < 8; ++dt) {
            bh8 vb = *(const bh8*)(vp + (size_t)(dt << 4) * Lk);
            o[dt] = __builtin_amdgcn_mfma_f32_16x16x32_bf16(pa, vb, o[dt], 0, 0, 0);
        }
    }
    float inv[4];
#pragma unroll
    for (int r = 0; r < 4; ++r) inv[r] = 1.0f / lrow[r];
#pragma unroll
    for (int dt = 0; dt < 8; ++dt) {
#pragma unroll
        for (int r = 0; r < 4; ++r) {
            int row = sb + (quad << 2) + r;
            int col = (h << 7) + (dt << 4) + l16;
            size_t idx = (size_t)row * D_TOT + col;
            float v = o[dt][r] * inv[r];
            if (accum) v += Out[idx];
            Out[idx] = v;
        }
    }
}

// ---------------- workspace layout (byte offsets), total ~132.5 MB (ws >= 215 MB verified R1) ----
static const u64 B_QF   = 0;           // fp32 [2304][3072]
static const u64 B_KF   = 28311552;
static const u64 B_VF   = 56623104;
static const u64 B_KIPF = 84934656;    // fp32 [128][3072]
static const u64 B_VIPF = 86507520;
static const u64 B_T1   = 88080384;    // fp32 [3][256][128]
static const u64 B_QB   = 88473600;    // bf16 [24][2304][128]
static const u64 B_KB   = 102629376;
static const u64 B_VT   = 116785152;   // bf16 [24][128][2304]
static const u64 B_KIPB = 130940928;   // bf16 [24][128][128]
static const u64 B_VIPT = 131727360;   // bf16 [24][128][128]

extern "C" void kernel_launch(void* const* d_in, const int* in_sizes, int n_in,
                              void* d_out, int out_size, void* d_ws, size_t ws_size,
                              hipStream_t stream) {
    (void)in_sizes; (void)n_in; (void)out_size; (void)ws_size;
    const float* x    = (const float*)d_in[0];
    const float* img  = (const float*)d_in[1];
    const float* rc   = (const float*)d_in[2];
    const float* rsn  = (const float*)d_in[3];
    const float* Wq   = (const float*)d_in[4];
    const float* bq   = (const float*)d_in[5];
    const float* Wk   = (const float*)d_in[6];
    const float* bk   = (const float*)d_in[7];
    const float* Wv   = (const float*)d_in[8];
    const float* bv   = (const float*)d_in[9];
    const float* qdn  = (const float*)d_in[10];
    const float* qup  = (const float*)d_in[11];
    const float* kdn  = (const float*)d_in[12];
    const float* kup  = (const float*)d_in[13];
    const float* vdn  = (const float*)d_in[14];
    const float* vup  = (const float*)d_in[15];
    const float* nqw  = (const float*)d_in[16];
    const float* nkw  = (const float*)d_in[17];
    const float* Wkip = (const float*)d_in[18];
    const float* Wvip = (const float*)d_in[19];

    float* qf   = (float*)((char*)d_ws + B_QF);
    float* kf   = (float*)((char*)d_ws + B_KF);
    float* vf   = (float*)((char*)d_ws + B_VF);
    float* kipf = (float*)((char*)d_ws + B_KIPF);
    float* vipf = (float*)((char*)d_ws + B_VIPF);
    float* t1   = (float*)((char*)d_ws + B_T1);
    u16*   Qb   = (u16*)((char*)d_ws + B_QB);
    u16*   Kb   = (u16*)((char*)d_ws + B_KB);
    u16*   Vt   = (u16*)((char*)d_ws + B_VT);
    u16*   Kipb = (u16*)((char*)d_ws + B_KIPB);
    u16*   Vipt = (u16*)((char*)d_ws + B_VIPT);
    float* outf = (float*)d_out;

    // zero the split-K atomic accumulation targets
    hipMemsetAsync((char*)d_ws + B_KIPF, 0, 2 * 1572864, stream);

    // 1) QKV projections: [2304][3072] = x @ W^T + bias (fp32 out)
    gemm_f32<<<dim3(18, 24, 1), dim3(256), 0, stream>>>(x, Wq, bq, qf, S_TOT, D_TOT, D_TOT, 0, 1);
    gemm_f32<<<dim3(18, 24, 1), dim3(256), 0, stream>>>(x, Wk, bk, kf, S_TOT, D_TOT, D_TOT, 0, 1);
    gemm_f32<<<dim3(18, 24, 1), dim3(256), 0, stream>>>(x, Wv, bv, vf, S_TOT, D_TOT, D_TOT, 0, 1);

    // 2) LoRA: down (t1 = x_cond @ down^T), then up (+= into rows 2048..2303)
    lora_down_k<<<dim3(32), dim3(256), 0, stream>>>(x, qdn, t1);
    lora_down_k<<<dim3(32), dim3(256), 0, stream>>>(x, kdn, t1 + 32768);
    lora_down_k<<<dim3(32), dim3(256), 0, stream>>>(x, vdn, t1 + 65536);
    gemm_f32<<<dim3(2, 24, 1), dim3(256), 0, stream>>>(t1,         qup, nullptr, qf + (size_t)BLK_R * D_TOT, 256, D_TOT, 128, 1, 1);
    gemm_f32<<<dim3(2, 24, 1), dim3(256), 0, stream>>>(t1 + 32768, kup, nullptr, kf + (size_t)BLK_R * D_TOT, 256, D_TOT, 128, 1, 1);
    gemm_f32<<<dim3(2, 24, 1), dim3(256), 0, stream>>>(t1 + 65536, vup, nullptr, vf + (size_t)BLK_R * D_TOT, 256, D_TOT, 128, 1, 1);

    // 3) IP projections: [128][3072] = img @ W_ip^T (split-K=8, atomic into zeroed fp32)
    gemm_f32<<<dim3(1, 24, 8), dim3(256), 0, stream>>>(img, Wkip, nullptr, kipf, TIP, D_TOT, DIP, 2, 8);
    gemm_f32<<<dim3(1, 24, 8), dim3(256), 0, stream>>>(img, Wvip, nullptr, vipf, TIP, D_TOT, DIP, 2, 8);

    // 4) norm (+rope) -> head-major bf16; V transposes
    norm_rope_k<1><<<dim3(13824), dim3(256), 0, stream>>>(qf, nqw, rc, rsn, Qb, S_TOT);
    norm_rope_k<1><<<dim3(13824), dim3(256), 0, stream>>>(kf, nkw, rc, rsn, Kb, S_TOT);
    norm_rope_k<0><<<dim3(768),   dim3(256), 0, stream>>>(kipf, nullptr, nullptr, nullptr, Kipb, TIP);
    transpose_v_k<<<dim3(36, 24), dim3(256), 0, stream>>>(vf, Vt, S_TOT);
    transpose_v_k<<<dim3(2, 24),  dim3(256), 0, stream>>>(vipf, Vipt, TIP);

    // 5) attention: main writes f32 out; IP attention accumulates (RMW)
    attn_k<<<dim3(36, 24), dim3(256), 0, stream>>>(Qb, Kb,   Vt,   outf, S_TOT, 64, 0);
    attn_k<<<dim3(36, 24), dim3(256), 0, stream>>>(Qb, Kipb, Vipt, outf, TIP,   0,  1);
}